// Round 12
// baseline (204.239 us; speedup 1.0000x reference)
//
#include <hip/hip_runtime.h>
#include <hip/hip_bf16.h>

typedef __attribute__((ext_vector_type(8))) short short8v;
typedef __attribute__((ext_vector_type(4))) float floatx4;

__device__ __forceinline__ unsigned short f2bf(float f) {
    unsigned b = __float_as_uint(f);
    b = (b + 0x7fffu + ((b >> 16) & 1u)) >> 16;
    return (unsigned short)b;
}
__device__ __forceinline__ float b2f(unsigned short u) {
    return __uint_as_float((unsigned)u << 16);
}

#define SCAN_NB 256

// ------ conv helpers (x -> bf16; W -> transposed bf16 [col][k]) -------------
__device__ __forceinline__ void conv_x(const float* __restrict__ x,
                                       unsigned short* __restrict__ xb, int i) {
    float4 v = reinterpret_cast<const float4*>(x)[i];
    ushort4 o;
    o.x = f2bf(v.x); o.y = f2bf(v.y); o.z = f2bf(v.z); o.w = f2bf(v.w);
    reinterpret_cast<ushort4*>(xb)[i] = o;
}
__device__ __forceinline__ void conv_wT(const float* __restrict__ W,
                                        unsigned short* __restrict__ wT,
                                        int j, int NC) {
    int k = j / (NC / 4), c4 = (j % (NC / 4)) * 4;
    float4 v = *reinterpret_cast<const float4*>(W + (size_t)k * NC + c4);
    wT[(size_t)(c4 + 0) * 256 + k] = f2bf(v.x);
    wT[(size_t)(c4 + 1) * 256 + k] = f2bf(v.y);
    wT[(size_t)(c4 + 2) * 256 + k] = f2bf(v.z);
    wT[(size_t)(c4 + 3) * 256 + k] = f2bf(v.w);
}

// ------ edge histogram (4 edges/thread) -------------------------------------
__global__ void k_hist(const int* __restrict__ ei, int* __restrict__ cnt, int E) {
    int e0 = (blockIdx.x * 256 + threadIdx.x) * 4;
    if (e0 >= E) return;
    int4 d4 = *reinterpret_cast<const int4*>(ei + E + e0);
    atomicAdd(&cnt[d4.x], 1);
    atomicAdd(&cnt[d4.y], 1);
    atomicAdd(&cnt[d4.z], 1);
    atomicAdd(&cnt[d4.w], 1);
}

// ------ scan A (block sums, +1 self-loop)  ||  conv part 1 ------------------
__launch_bounds__(256)
__global__ void k_scan_a(const int* __restrict__ cnt, int* __restrict__ bsum, int N,
                         const float* __restrict__ x, unsigned short* __restrict__ xb,
                         int xh1,
                         const float* __restrict__ Wg, unsigned short* __restrict__ wbT,
                         int TG) {
    int b = blockIdx.x, t = threadIdx.x;
    if (b >= SCAN_NB) {
        int i = (b - SCAN_NB) * 256 + t;
        if (i < xh1) conv_x(x, xb, i);
        else if (i < xh1 + TG) conv_wT(Wg, wbT, i - xh1, 256);
        return;
    }
    __shared__ int sh[256];
    int chunk = (N + SCAN_NB - 1) / SCAN_NB;
    int idx = b * chunk + t;
    sh[t] = (t < chunk && idx < N) ? (cnt[idx] + 1) : 0;   // +1: self-loop
    __syncthreads();
    for (int off = 128; off > 0; off >>= 1) {
        if (t < off) sh[t] += sh[t + off];
        __syncthreads();
    }
    if (t == 0) bsum[b] = sh[0];
}

// ------ scan BC (row starts, self-loop pre-place)  ||  conv part 2 ----------
__launch_bounds__(256)
__global__ void k_scan_bc(const int* __restrict__ cnt, const int* __restrict__ bsum,
                          int* __restrict__ row_start, int* __restrict__ cursor,
                          unsigned short* __restrict__ ssrc, int N,
                          const float* __restrict__ x, unsigned short* __restrict__ xb,
                          int xh1, int xh2,
                          const float* __restrict__ Wl, unsigned short* __restrict__ wlbT,
                          int TL) {
    int b = blockIdx.x, t = threadIdx.x;
    if (b >= SCAN_NB) {
        int i = (b - SCAN_NB) * 256 + t;
        if (i < xh2) conv_x(x, xb, xh1 + i);
        else if (i < xh2 + TL) conv_wT(Wl, wlbT, i - xh2, 64);
        return;
    }
    __shared__ int shb[256];
    __shared__ int sh[256];
    shb[t] = bsum[t];
    __syncthreads();
    for (int off = 1; off < 256; off <<= 1) {
        int v = (t >= off) ? shb[t - off] : 0;
        __syncthreads();
        shb[t] += v;
        __syncthreads();
    }
    int boff = (b == 0) ? 0 : shb[b - 1];

    int chunk = (N + SCAN_NB - 1) / SCAN_NB;
    int idx = b * chunk + t;
    int v = (t < chunk && idx < N) ? (cnt[idx] + 1) : 0;
    sh[t] = v;
    __syncthreads();
    for (int off = 1; off < 256; off <<= 1) {
        int u = (t >= off) ? sh[t - off] : 0;
        __syncthreads();
        sh[t] += u;
        __syncthreads();
    }
    if (t < chunk && idx < N) {
        int ex = boff + sh[t] - v;
        row_start[idx] = ex;
        cursor[idx] = ex + 1;            // slot 0 = self-loop
        ssrc[ex] = (unsigned short)idx;
    }
}

// ------ fused: GEMM1 (LDS-staged, 8 waves, +attn epilogue) || scatter -------
__launch_bounds__(512)
__global__ void k_gs(const unsigned short* __restrict__ A,
                     const unsigned short* __restrict__ BT,   // [col][k] bf16
                     const float* __restrict__ att_src, const float* __restrict__ att_dst,
                     unsigned short* __restrict__ hb,
                     float* __restrict__ a_src, float* __restrict__ a_dst,
                     int M, int RB, int GB1,
                     const int* __restrict__ ei, int* __restrict__ cursor,
                     unsigned short* __restrict__ ssrc, int E) {
    __shared__ unsigned short BsT[64 * 264];   // [col][k], stride 264 (bank-balanced)
    const int b = blockIdx.x;
    const int tid = threadIdx.x;
    if (b >= GB1) {
        int e0 = ((b - GB1) * 512 + tid) * 4;
        if (e0 >= E) return;
        int4 s4 = *reinterpret_cast<const int4*>(ei + e0);
        int4 d4 = *reinterpret_cast<const int4*>(ei + E + e0);
        int p0 = atomicAdd(&cursor[d4.x], 1);
        int p1 = atomicAdd(&cursor[d4.y], 1);
        int p2 = atomicAdd(&cursor[d4.z], 1);
        int p3 = atomicAdd(&cursor[d4.w], 1);
        ssrc[p0] = (unsigned short)s4.x;
        ssrc[p1] = (unsigned short)s4.y;
        ssrc[p2] = (unsigned short)s4.z;
        ssrc[p3] = (unsigned short)s4.w;
        return;
    }
    const int nt = b / RB;
    const int tM = (b - nt * RB) * 128;

#pragma unroll
    for (int it = 0; it < 4; ++it) {
        int chunk = it * 512 + tid;
        int col = chunk >> 5;
        int k0 = (chunk & 31) * 8;
        short8v v = *reinterpret_cast<const short8v*>(BT + (size_t)(nt * 64 + col) * 256 + k0);
        *reinterpret_cast<short8v*>(&BsT[col * 264 + k0]) = v;
    }
    __syncthreads();

    const int w  = tid >> 6;
    const int l  = tid & 63;
    const int lg = l >> 4;
    const int lr = l & 15;

    int rowA = tM + w * 16 + lr;
    if (rowA > M - 1) rowA = M - 1;
    const unsigned short* Arow = A + (size_t)rowA * 256 + lg * 8;
    short8v av[8];
#pragma unroll
    for (int kt = 0; kt < 8; ++kt)
        av[kt] = *reinterpret_cast<const short8v*>(Arow + kt * 32);

    floatx4 acc[4] = {};
#pragma unroll
    for (int kt = 0; kt < 8; ++kt) {
#pragma unroll
        for (int n = 0; n < 4; ++n) {
            short8v bv = *reinterpret_cast<const short8v*>(&BsT[(n * 16 + lr) * 264 + kt * 32 + lg * 8]);
            acc[n] = __builtin_amdgcn_mfma_f32_16x16x32_bf16(av[kt], bv, acc[n], 0, 0, 0);
        }
    }

    float ps[2][4] = {}, pd[2][4] = {};
#pragma unroll
    for (int n = 0; n < 4; ++n) {
        int hd2 = n >> 1;
        float asv = att_src[(nt * 2 + hd2) * 32 + (n & 1) * 16 + lr];
        float adv = att_dst[(nt * 2 + hd2) * 32 + (n & 1) * 16 + lr];
        int col = nt * 64 + n * 16 + lr;
#pragma unroll
        for (int r = 0; r < 4; ++r) {
            int row = tM + w * 16 + lg * 4 + r;  // C/D: row=(lane>>4)*4+reg
            float v = acc[n][r];
            if (row < M) hb[(size_t)row * 256 + col] = f2bf(v);
            ps[hd2][r] += v * asv;
            pd[hd2][r] += v * adv;
        }
    }
#pragma unroll
    for (int off = 1; off < 16; off <<= 1) {
#pragma unroll
        for (int hd2 = 0; hd2 < 2; ++hd2)
#pragma unroll
            for (int r = 0; r < 4; ++r) {
                ps[hd2][r] += __shfl_xor(ps[hd2][r], off, 64);
                pd[hd2][r] += __shfl_xor(pd[hd2][r], off, 64);
            }
    }
    if (lr == 0) {
#pragma unroll
        for (int hd2 = 0; hd2 < 2; ++hd2)
#pragma unroll
            for (int r = 0; r < 4; ++r) {
                int row = tM + w * 16 + lg * 4 + r;
                if (row < M) {
                    a_src[(size_t)row * 8 + nt * 2 + hd2] = ps[hd2][r];
                    a_dst[(size_t)row * 8 + nt * 2 + hd2] = pd[hd2][r];
                }
            }
    }
}

// ------ GEMM2 (LDS-staged, 8 waves): out[M,64] = g @ W_lin + b_lin ----------
__launch_bounds__(512)
__global__ void k_gemm2(const unsigned short* __restrict__ A,
                        const unsigned short* __restrict__ BT,  // [col][k]
                        float* __restrict__ C,
                        const float* __restrict__ bias, int M) {
    __shared__ unsigned short BsT[64 * 264];
    const int tid = threadIdx.x;
    const int tM = blockIdx.x * 128;

#pragma unroll
    for (int it = 0; it < 4; ++it) {
        int chunk = it * 512 + tid;
        int col = chunk >> 5;
        int k0 = (chunk & 31) * 8;
        short8v v = *reinterpret_cast<const short8v*>(BT + (size_t)col * 256 + k0);
        *reinterpret_cast<short8v*>(&BsT[col * 264 + k0]) = v;
    }
    __syncthreads();

    const int w  = tid >> 6;
    const int l  = tid & 63;
    const int lg = l >> 4;
    const int lr = l & 15;

    int rowA = tM + w * 16 + lr;
    if (rowA > M - 1) rowA = M - 1;
    const unsigned short* Arow = A + (size_t)rowA * 256 + lg * 8;

    floatx4 acc[4] = {};
#pragma unroll
    for (int kt = 0; kt < 8; ++kt) {
        short8v av = *reinterpret_cast<const short8v*>(Arow + kt * 32);
#pragma unroll
        for (int n = 0; n < 4; ++n) {
            short8v bv = *reinterpret_cast<const short8v*>(&BsT[(n * 16 + lr) * 264 + kt * 32 + lg * 8]);
            acc[n] = __builtin_amdgcn_mfma_f32_16x16x32_bf16(av, bv, acc[n], 0, 0, 0);
        }
    }
#pragma unroll
    for (int n = 0; n < 4; ++n) {
        int col = n * 16 + lr;
        float badd = bias[col];
#pragma unroll
        for (int r = 0; r < 4; ++r) {
            int row = tM + w * 16 + lg * 4 + r;
            if (row < M) C[(size_t)row * 64 + col] = acc[n][r] + badd;
        }
    }
}

// ------ fused aggregate: 2 edges per wave-pass, 8 ch/lane -------------------
// lane: half = lane>>5 (edge of pair), li = lane&31 (8-ch group), hd = li>>2.
// Halves combined at the end via shfl_xor(32). Lanes 0-31 write the row.
__launch_bounds__(256)
__global__ void k_agg(const int* __restrict__ row_start, const int* __restrict__ row_end,
                      const unsigned short* __restrict__ sorted_src,
                      const float* __restrict__ a_src, const float* __restrict__ a_dst,
                      const unsigned short* __restrict__ hb,
                      const float* __restrict__ bias_gat,
                      unsigned short* __restrict__ gb, int N) {
    int n = blockIdx.x * 4 + (threadIdx.x >> 6);
    if (n >= N) return;
    const int lane = threadIdx.x & 63;
    const int half = lane >> 5;
    const int li   = lane & 31;
    const int hd   = li >> 2;
    int start = row_start[n], end = row_end[n];
    float ad = a_dst[(size_t)n * 8 + hd];
    float accA[8] = {}, accB[8] = {};
    float denA = 0.f, denB = 0.f;
    for (int j0 = start; j0 < end; j0 += 64) {
        int idx = j0 + lane;
        int sv = (idx < end) ? (int)sorted_src[idx] : 0;
        int cnt = end - j0; if (cnt > 64) cnt = 64;
        int jj = 0;
        for (; jj + 3 < cnt; jj += 4) {           // 4 edges (2 pairs) / iter
            int sA = __shfl(sv, jj + half);
            int sB = __shfl(sv, jj + 2 + half);
            float vA = a_src[(size_t)sA * 8 + hd] + ad;
            float vB = a_src[(size_t)sB * 8 + hd] + ad;
            short8v hA = *reinterpret_cast<const short8v*>(hb + (size_t)sA * 256 + li * 8);
            short8v hB = *reinterpret_cast<const short8v*>(hb + (size_t)sB * 256 + li * 8);
            vA = vA > 0.f ? vA : 0.2f * vA;
            vB = vB > 0.f ? vB : 0.2f * vB;
            float eA = __expf(vA), eB = __expf(vB);
            denA += eA; denB += eB;
#pragma unroll
            for (int q = 0; q < 8; ++q) {
                accA[q] += eA * b2f((unsigned short)hA[q]);
                accB[q] += eB * b2f((unsigned short)hB[q]);
            }
        }
        for (; jj < cnt; jj += 2) {               // pair tail
            int jp = jj + half;
            int s = __shfl(sv, (jp < cnt) ? jp : 0);
            float v = a_src[(size_t)s * 8 + hd] + ad;
            v = v > 0.f ? v : 0.2f * v;
            float e = (jp < cnt) ? __expf(v) : 0.f;
            short8v h8 = *reinterpret_cast<const short8v*>(hb + (size_t)s * 256 + li * 8);
            denA += e;
#pragma unroll
            for (int q = 0; q < 8; ++q)
                accA[q] += e * b2f((unsigned short)h8[q]);
        }
    }
    float den = denA + denB;
    den += __shfl_xor(den, 32, 64);
    float inv = 1.0f / (den + 1e-16f);
    float4 b0 = reinterpret_cast<const float4*>(bias_gat + li * 8)[0];
    float4 b1 = reinterpret_cast<const float4*>(bias_gat + li * 8)[1];
    float bb[8] = {b0.x, b0.y, b0.z, b0.w, b1.x, b1.y, b1.z, b1.w};
    short8v o;
#pragma unroll
    for (int q = 0; q < 8; ++q) {
        float s = accA[q] + accB[q];
        s += __shfl_xor(s, 32, 64);
        o[q] = (short)f2bf(fmaxf(s * inv + bb[q], 0.f));
    }
    if (half == 0)
        *reinterpret_cast<short8v*>(gb + (size_t)n * 256 + li * 8) = o;
}

extern "C" void kernel_launch(void* const* d_in, const int* in_sizes, int n_in,
                              void* d_out, int out_size, void* d_ws, size_t ws_size,
                              hipStream_t stream) {
    const float* x        = (const float*)d_in[0];
    const int*   ei       = (const int*)d_in[1];
    const float* W_gat    = (const float*)d_in[2];
    const float* att_src  = (const float*)d_in[3];
    const float* att_dst  = (const float*)d_in[4];
    const float* bias_gat = (const float*)d_in[5];
    const float* W_lin    = (const float*)d_in[6];
    const float* b_lin    = (const float*)d_in[7];
    float* out = (float*)d_out;

    const int N  = in_sizes[0] / 256;   // 50000
    const int E  = in_sizes[1] / 2;     // 800000
    const int EE = E + N;

    char* ws = (char*)d_ws;
    size_t off = 0;
    auto alloc = [&](size_t bytes) -> void* {
        void* p = ws + off;
        off = (off + bytes + 255) & ~(size_t)255;
        return p;
    };
    unsigned short* hb       = (unsigned short*)alloc((size_t)N * 256 * 2);
    float*          a_srcv   = (float*)alloc((size_t)N * 8 * 4);
    float*          a_dstv   = (float*)alloc((size_t)N * 8 * 4);
    int*            cnt      = (int*)alloc((size_t)N * 4);
    int*            rowst    = (int*)alloc((size_t)N * 4);
    int*            cursor   = (int*)alloc((size_t)N * 4);
    int*            bsum     = (int*)alloc(SCAN_NB * 4);
    unsigned short* ssrc     = (unsigned short*)alloc((size_t)EE * 2);
    unsigned short* xb       = (unsigned short*)alloc((size_t)N * 256 * 2);  // reused as gb
    unsigned short* wbT      = (unsigned short*)alloc(256 * 256 * 2);
    unsigned short* wlbT     = (unsigned short*)alloc(64 * 256 * 2);

    const int n0  = N * 256 / 4;        // x f4 chunks
    const int xh1 = n0 / 2;
    const int xh2 = n0 - xh1;
    const int TG  = 256 * 256 / 4;
    const int TL  = 256 * 64 / 4;

    hipMemsetAsync(cnt, 0, (size_t)N * 4, stream);

    // edge histogram
    k_hist<<<(E / 4 + 255) / 256, 256, 0, stream>>>(ei, cnt, E);

    // scan A || conv(x first half, W_gat^T)
    int cb1 = (xh1 + TG + 255) / 256;
    k_scan_a<<<SCAN_NB + cb1, 256, 0, stream>>>(cnt, bsum, N, x, xb, xh1, W_gat, wbT, TG);

    // scan BC || conv(x second half, W_lin^T)
    int cb2 = (xh2 + TL + 255) / 256;
    k_scan_bc<<<SCAN_NB + cb2, 256, 0, stream>>>(cnt, bsum, rowst, cursor, ssrc, N,
                                                 x, xb, xh1, xh2, W_lin, wlbT, TL);

    // fused GEMM1(+attn epilogue) || scatter
    const int RB  = (N + 127) / 128;
    const int GB1 = RB * 4;
    const int SB  = (E / 4 + 511) / 512;
    k_gs<<<GB1 + SB, 512, 0, stream>>>(xb, wbT, att_src, att_dst, hb, a_srcv, a_dstv,
                                       N, RB, GB1, ei, cursor, ssrc, E);

    // fused segment softmax + aggregate + bias + relu -> bf16 (into xb as gb)
    k_agg<<<(N + 3) / 4, 256, 0, stream>>>(rowst, cursor, ssrc, a_srcv, a_dstv, hb,
                                           bias_gat, xb, N);

    // GEMM2: out = g @ W_lin + b_lin
    k_gemm2<<<(N + 127) / 128, 512, 0, stream>>>(xb, wlbT, out, b_lin, N);
}